// Round 2
// baseline (11839.033 us; speedup 1.0000x reference)
//
#include <hip/hip_runtime.h>
#include <cstdint>
#include <cstddef>

// ---------------------------------------------------------------------------
// FieldLstmEncoder on MI355X (gfx950)   B=128 S=512 UNI=512 HID=1024 FLD=128
// PERSISTENT version: one 256-block x 512-thread kernel runs all 512 steps.
// Block nb owns H-cols [4nb,4nb+4) across all 4 gates and all 128 sorted rows.
// W1 slice (16x1536) staged in LDS ONCE; c/h-own kept in registers; h state
// ping-pongs in global bf16; hand-rolled device-scope grid barrier per step.
// ---------------------------------------------------------------------------

typedef __bf16 bf16;
typedef __bf16 bf16x8 __attribute__((ext_vector_type(8)));
typedef float floatx4 __attribute__((ext_vector_type(4)));

#define B_ 128
#define S_ 512
#define UNI_ 512
#define HID_ 1024
#define FLD_ 128
#define K1_ 1536
#define BS_STRIDE 1544  // 1536 + 8 bf16 pad (16B) -> bank spread
#define NBLK 256
#define NSLOT 64        // release-broadcast slots (128B apart) to cut spin contention

__device__ __forceinline__ float sigf(float x) { return 1.0f / (1.0f + __expf(-x)); }

// ---------------------------------------------------------------------------
__global__ __launch_bounds__(128) void sort_kernel(const int* __restrict__ len,
                                                   int* __restrict__ perm,
                                                   int* __restrict__ lens) {
  int i = threadIdx.x;  // 128 threads, 1 block
  int li = len[i];
  int r = 0;
  for (int j = 0; j < B_; ++j) {
    int lj = len[j];
    r += (lj > li) || (lj == li && j < i) ? 1 : 0;
  }
  perm[r] = i;
  lens[r] = li;
}

__global__ __launch_bounds__(256) void conv_w(const float* __restrict__ W1,
                                              const float* __restrict__ W2,
                                              bf16* __restrict__ W1b,
                                              bf16* __restrict__ W2b) {
  int i = blockIdx.x * 256 + threadIdx.x;
  if (i < 4096 * K1_) W1b[i] = (bf16)W1[i];
  else {
    int j = i - 4096 * K1_;
    if (j < 2048 * FLD_) W2b[j] = (bf16)W2[j];
  }
}

// zero h double-buffer + barrier state (must re-zero every launch for graph replay)
__global__ __launch_bounds__(256) void zero_state(bf16* __restrict__ h0,
                                                  bf16* __restrict__ h1,
                                                  int* __restrict__ bar) {
  int i = blockIdx.x * 256 + threadIdx.x;  // 131072
  h0[i] = (bf16)0.0f;
  h1[i] = (bf16)0.0f;
  if (i < 32 + NSLOT * 32) bar[i] = 0;
}

// x,f fp32 -> bf16, rows permuted to sorted order, layout [t][rs][*] so each
// step's A-slice is one contiguous chunk. grid (S, B), 256 thr.
__global__ __launch_bounds__(256) void conv_xf(const float* __restrict__ x,
                                               const float* __restrict__ f,
                                               const int* __restrict__ perm,
                                               bf16* __restrict__ xbf,
                                               bf16* __restrict__ fbf) {
  int t = blockIdx.x, rs = blockIdx.y, tid = threadIdx.x;
  int b = perm[rs];
  const float* xs = x + ((size_t)b * S_ + t) * UNI_;
  bf16* xd = xbf + ((size_t)t * B_ + rs) * UNI_;
  xd[tid] = (bf16)xs[tid];
  xd[tid + 256] = (bf16)xs[tid + 256];
  if (tid < FLD_) {
    fbf[((size_t)t * B_ + rs) * FLD_ + tid] =
        (bf16)f[((size_t)b * S_ + t) * FLD_ + tid];
  }
}

// zero out[b][t][:] for t >= len[b]. grid (S, B), 256 thr x float4.
__global__ __launch_bounds__(256) void zero_tail(const int* __restrict__ len,
                                                 float* __restrict__ out) {
  int t = blockIdx.x, b = blockIdx.y;
  if (t < len[b]) return;
  float4 z = {0.0f, 0.0f, 0.0f, 0.0f};
  float4* o = (float4*)(out + ((size_t)b * S_ + t) * HID_);
  o[threadIdx.x] = z;
}

// ---------------------------------------------------------------------------
// Device-scope grid barrier. bar[0] = arrive counter; bar[32 + s*32] = release
// slots (one generation int per 128B line, 4 blocks poll each slot).
// __threadfence() is agent-scope seq_cst -> handles cross-XCD L2 non-coherence.
// ---------------------------------------------------------------------------
__device__ __forceinline__ void grid_barrier(int* __restrict__ bar, int t) {
  __syncthreads();
  if (threadIdx.x == 0) {
    int* cnt = bar;
    int* slots = bar + 32;
    __threadfence();  // release: h_nxt/out stores visible at agent scope
    int prev = __hip_atomic_fetch_add(cnt, 1, __ATOMIC_RELAXED,
                                      __HIP_MEMORY_SCOPE_AGENT);
    if (prev == NBLK - 1) {
      // last arriver: sync with all arrivers, reset, release everyone
      __threadfence();  // acquire side: all arrivers' stores visible
      __hip_atomic_store(cnt, 0, __ATOMIC_RELAXED, __HIP_MEMORY_SCOPE_AGENT);
      __threadfence();  // order cnt reset before slot release
#pragma unroll
      for (int s = 0; s < NSLOT; ++s)
        __hip_atomic_store(&slots[s * 32], t + 1, __ATOMIC_RELAXED,
                           __HIP_MEMORY_SCOPE_AGENT);
    } else {
      int* my = &slots[(blockIdx.x & (NSLOT - 1)) * 32];
      while (__hip_atomic_load(my, __ATOMIC_RELAXED,
                               __HIP_MEMORY_SCOPE_AGENT) <= t)
        __builtin_amdgcn_s_sleep(2);
      __threadfence();  // acquire: make released data visible to this block
    }
  }
  __syncthreads();
}

// ---------------------------------------------------------------------------
// Persistent LSTM kernel: all 512 timesteps.
// ---------------------------------------------------------------------------
__global__ __launch_bounds__(512, 2) void lstm_persistent(
    const bf16* __restrict__ xbf,     // [S][128][UNI] sorted rows
    const bf16* __restrict__ fbf,     // [S][128][FLD] sorted rows
    const bf16* __restrict__ W1b,     // [4H][K1]
    const bf16* __restrict__ W2b,     // [2H][FLD]
    const float* __restrict__ bias1,  // [4H]
    const float* __restrict__ bias2,  // [2H]
    bf16* __restrict__ ha,            // [128][HID] h buffer (even t reads)
    bf16* __restrict__ hb,            // [128][HID] h buffer (odd t reads)
    const int* __restrict__ perm_g,   // [128] sorted -> orig
    const int* __restrict__ lens_g,   // [128] sorted desc
    float* __restrict__ out,
    int* __restrict__ bar) {
  __shared__ bf16 Bs[16 * BS_STRIDE];  // 49408 B  W1 slice, staged once
  __shared__ bf16 Ws2[8 * 136];        //  2176 B  W2 slice, staged once
  __shared__ float pre_s[128][17];     //  8704 B
  __shared__ float rd_s[128][9];       //  4608 B
  __shared__ int lens_s[128];
  __shared__ int perm_s[128];
  // total ~66 KB -> >=2 blocks/CU capacity; grid 256 = #CUs -> all co-resident

  const int tid = threadIdx.x;
  const int nb = blockIdx.x;
  const int c0 = nb * 4;

  // ---- one-time staging ----
  {  // W1 slice: 16 gate-rows x 1536
    const int n = tid >> 5;  // 0..15
    const int s = tid & 31;
    const int wrow = (n >> 2) * HID_ + c0 + (n & 3);
    const bf16* src = W1b + (size_t)wrow * K1_;
    bf16* dst = Bs + n * BS_STRIDE;
#pragma unroll
    for (int p = 0; p < 6; ++p) {
      int off = (p * 32 + s) * 8;
      *(bf16x8*)(dst + off) = *(const bf16x8*)(src + off);
    }
  }
  if (tid < 128) {
    lens_s[tid] = lens_g[tid];
    perm_s[tid] = perm_g[tid];
  }
  if (tid >= 128 && tid < 256) {  // W2 slice: 8 rows (r,d gates x 4 cols) x 128
    int q = tid - 128;            // 0..127
    int r = q >> 4, s = q & 15;
    int w2row = (r >> 2) * HID_ + c0 + (r & 3);
    *(bf16x8*)(Ws2 + r * 136 + s * 8) =
        *(const bf16x8*)(W2b + (size_t)w2row * FLD_ + s * 8);
  }
  __syncthreads();

  // ---- per-thread constants ----
  const int wave = tid >> 6;
  const int lane = tid & 63;
  const int quad = lane >> 4;
  const int l16 = lane & 15;
  const int m = wave * 16 + l16;  // A row (sorted batch index)
  const int kq = quad * 8;
  const bf16* bsl = Bs + l16 * BS_STRIDE + kq;
  const bf16* ws2p = Ws2 + ((((l16 >> 2) & 1) * 4 + (l16 & 3)) * 136) + kq;
  const int wlen = lens_s[wave * 16];  // lens sorted desc -> wave-max len

  // update-phase mapping: thread -> (row, col)
  const int urow = tid >> 2;
  const int ucc = tid & 3;
  const int ucol = c0 + ucc;
  const float b1i = bias1[ucol];
  const float b1j = bias1[HID_ + ucol];
  const float b1f = bias1[2 * HID_ + ucol];
  const float b1o = bias1[3 * HID_ + ucol];
  const float b2r = bias2[ucol];
  const float b2d = bias2[HID_ + ucol];
  const int ulen = lens_s[urow];
  const size_t hidx = (size_t)urow * HID_ + ucol;
  float* outrow = out + (size_t)perm_s[urow] * (S_ * HID_) + ucol;

  float c_my = 0.0f;  // cell state: (row,col) owned by exactly this thread
  float h_my = 0.0f;  // this thread's h (fp32 master copy; bf16 in global)

  for (int t = 0; t < S_; ++t) {
    const bf16* hcur = (t & 1) ? hb : ha;
    bf16* hnxt = (t & 1) ? ha : hb;

    if (t < wlen) {
      floatx4 acc_a = {0.f, 0.f, 0.f, 0.f};
      floatx4 acc_b = {0.f, 0.f, 0.f, 0.f};
      floatx4 accr = {0.f, 0.f, 0.f, 0.f};
      const bf16* xrow = xbf + ((size_t)t * B_ + m) * UNI_ + kq;
      const bf16* hrow = hcur + (size_t)m * HID_ + kq;

      // ---- K in [0,512): A = x_t ----
#pragma unroll
      for (int kc = 0; kc < UNI_; kc += 64) {
        bf16x8 a0 = *(const bf16x8*)(xrow + kc);
        bf16x8 b0 = *(const bf16x8*)(bsl + kc);
        bf16x8 a1 = *(const bf16x8*)(xrow + kc + 32);
        bf16x8 b1 = *(const bf16x8*)(bsl + kc + 32);
        acc_a = __builtin_amdgcn_mfma_f32_16x16x32_bf16(a0, b0, acc_a, 0, 0, 0);
        acc_b = __builtin_amdgcn_mfma_f32_16x16x32_bf16(a1, b1, acc_b, 0, 0, 0);
      }
      // ---- K in [512,1536): A = h_prev ----
#pragma unroll 8
      for (int kc = 0; kc < HID_; kc += 64) {
        bf16x8 a0 = *(const bf16x8*)(hrow + kc);
        bf16x8 b0 = *(const bf16x8*)(bsl + UNI_ + kc);
        bf16x8 a1 = *(const bf16x8*)(hrow + kc + 32);
        bf16x8 b1 = *(const bf16x8*)(bsl + UNI_ + kc + 32);
        acc_a = __builtin_amdgcn_mfma_f32_16x16x32_bf16(a0, b0, acc_a, 0, 0, 0);
        acc_b = __builtin_amdgcn_mfma_f32_16x16x32_bf16(a1, b1, acc_b, 0, 0, 0);
      }
      // ---- field GEMM (K=128), B from LDS ----
      {
        const bf16* frow = fbf + ((size_t)t * B_ + m) * FLD_ + kq;
#pragma unroll
        for (int kc = 0; kc < FLD_; kc += 32) {
          bf16x8 a0 = *(const bf16x8*)(frow + kc);
          bf16x8 b0 = *(const bf16x8*)(ws2p + kc);
          accr = __builtin_amdgcn_mfma_f32_16x16x32_bf16(a0, b0, accr, 0, 0, 0);
        }
      }
      // ---- acc -> LDS (C/D: col=l16, row=quad*4+r) ----
      const int row0 = wave * 16 + quad * 4;
#pragma unroll
      for (int r = 0; r < 4; ++r) {
        pre_s[row0 + r][l16] = acc_a[r] + acc_b[r];
        if (l16 < 8) rd_s[row0 + r][l16] = accr[r];
      }
    }
    __syncthreads();

    // ---- LSTM elementwise update (c, h in registers) ----
    if (t < ulen) {
      float iv = pre_s[urow][ucc] + b1i;
      float jv = pre_s[urow][4 + ucc] + b1j;
      float fv = pre_s[urow][8 + ucc] + b1f;
      float ov = pre_s[urow][12 + ucc] + b1o;
      float rv = rd_s[urow][ucc] + b2r;
      float dv = rd_s[urow][4 + ucc] + b2d;
      c_my = sigf(fv + 1.0f) * c_my + sigf(iv) * tanhf(jv) + sigf(rv) * tanhf(dv);
      h_my = sigf(ov) * tanhf(c_my);
      outrow[(size_t)t * HID_] = h_my;
    }
    // unconditional: keeps frozen rows' h present in both ping-pong buffers
    hnxt[hidx] = (bf16)h_my;

    grid_barrier(bar, t);  // h_nxt fully visible before any block starts t+1
  }

  // ---- final h, c tails (fp32 masters from registers) ----
  {
    const size_t base = (size_t)B_ * S_ * HID_;
    const size_t prow = (size_t)perm_s[urow] * HID_ + ucol;
    out[base + prow] = h_my;
    out[base + (size_t)B_ * HID_ + prow] = c_my;
  }
}

// ---------------------------------------------------------------------------
extern "C" void kernel_launch(void* const* d_in, const int* in_sizes, int n_in,
                              void* d_out, int out_size, void* d_ws, size_t ws_size,
                              hipStream_t stream) {
  const float* x = (const float*)d_in[0];
  const float* f = (const float*)d_in[1];
  const int* len = (const int*)d_in[2];
  const float* W1 = (const float*)d_in[3];
  const float* b1 = (const float*)d_in[4];
  const float* W2 = (const float*)d_in[5];
  const float* b2 = (const float*)d_in[6];
  float* out = (float*)d_out;

  char* ws = (char*)d_ws;
  bf16* W1b = (bf16*)(ws);                    // 12,582,912
  bf16* W2b = (bf16*)(ws + 12582912);         //    524,288
  bf16* xbf = (bf16*)(ws + 13107200);         // 67,108,864  [S][B][UNI]
  bf16* fbf = (bf16*)(ws + 80216064);         // 16,777,216  [S][B][FLD]
  bf16* h0 = (bf16*)(ws + 96993280);          //    262,144
  bf16* h1 = (bf16*)(ws + 97255424);          //    262,144
  int* perm = (int*)(ws + 97517568);          //        512
  int* lens = (int*)(ws + 97518080);          //        512
  int* bar = (int*)(ws + 97518592);           //      8,320 (cnt + 64 slots)
  // total ~97.5 MB

  sort_kernel<<<1, 128, 0, stream>>>(len, perm, lens);
  conv_w<<<(4096 * K1_ + 2048 * FLD_ + 255) / 256, 256, 0, stream>>>(W1, W2, W1b, W2b);
  zero_state<<<512, 256, 0, stream>>>(h0, h1, bar);
  conv_xf<<<dim3(S_, B_), 256, 0, stream>>>(x, f, perm, xbf, fbf);
  zero_tail<<<dim3(S_, B_), 256, 0, stream>>>(len, out);

  lstm_persistent<<<NBLK, 512, 0, stream>>>(xbf, fbf, W1b, W2b, b1, b2, h0, h1,
                                            perm, lens, out, bar);
}